// Round 1
// baseline (2202.834 us; speedup 1.0000x reference)
//
#include <hip/hip_runtime.h>

constexpr int N_NODES = 50000;
constexpr int N_EDGES = 1600000;
constexpr int NREL    = 12;
constexpr int F_INPUT = 64;
constexpr int HID     = 128;
constexpr int NCLS    = 10;
constexpr int NGRAPH  = 256;
constexpr int NSEG    = N_NODES * NREL;       // 600000
constexpr int CHUNK   = 1024;
constexpr int NCHUNK  = (NSEG + CHUNK - 1) / CHUNK;  // 586
constexpr float BN_EPS = 1e-5f;

// ---------------- CSR build ----------------

__global__ void count_edges(const int* __restrict__ dst, const int* __restrict__ et,
                            int* __restrict__ cnt) {
    int e = blockIdx.x * blockDim.x + threadIdx.x;
    if (e < N_EDGES) atomicAdd(&cnt[dst[e] * NREL + et[e]], 1);
}

__global__ void scan_a(const int* __restrict__ cnt, int* __restrict__ csum) {
    __shared__ int red[256];
    int b = blockIdx.x, t = threadIdx.x;
    int base = b * CHUNK + t * 4;
    int s = 0;
#pragma unroll
    for (int j = 0; j < 4; ++j) {
        int i = base + j;
        if (i < NSEG) s += cnt[i];
    }
    red[t] = s;
    __syncthreads();
    for (int d = 128; d > 0; d >>= 1) {
        if (t < d) red[t] += red[t + d];
        __syncthreads();
    }
    if (t == 0) csum[b] = red[0];
}

__global__ void scan_b(const int* __restrict__ csum, int* __restrict__ coff) {
    __shared__ int s[1024];
    int t = threadIdx.x;
    s[t] = (t < NCHUNK) ? csum[t] : 0;
    __syncthreads();
    for (int d = 1; d < 1024; d <<= 1) {
        int v = (t >= d) ? s[t - d] : 0;
        __syncthreads();
        s[t] += v;
        __syncthreads();
    }
    if (t < NCHUNK) coff[t] = (t == 0) ? 0 : s[t - 1];
}

__global__ void scan_c(const int* __restrict__ cnt, const int* __restrict__ coff,
                       int* __restrict__ off, int* __restrict__ cursor) {
    __shared__ int ts[256];
    int b = blockIdx.x, t = threadIdx.x;
    int base = b * CHUNK + t * 4;
    int c[4];
    int s = 0;
#pragma unroll
    for (int j = 0; j < 4; ++j) {
        int i = base + j;
        c[j] = (i < NSEG) ? cnt[i] : 0;
        s += c[j];
    }
    ts[t] = s;
    __syncthreads();
    for (int d = 1; d < 256; d <<= 1) {
        int v = (t >= d) ? ts[t - d] : 0;
        __syncthreads();
        ts[t] += v;
        __syncthreads();
    }
    int run = coff[b] + ((t == 0) ? 0 : ts[t - 1]);
#pragma unroll
    for (int j = 0; j < 4; ++j) {
        int i = base + j;
        if (i < NSEG) {
            off[i] = run;
            cursor[i] = run;
            run += c[j];
        }
    }
    if (b == 0 && t == 0) off[NSEG] = N_EDGES;
}

__global__ void fill_csr(const int* __restrict__ src, const int* __restrict__ dst,
                         const int* __restrict__ et, int* __restrict__ cursor,
                         int* __restrict__ csr_src) {
    int e = blockIdx.x * blockDim.x + threadIdx.x;
    if (e < N_EDGES) {
        int s = dst[e] * NREL + et[e];
        int p = atomicAdd(&cursor[s], 1);
        csr_src[p] = src[e];
    }
}

// ---------------- fused RGCN layer: segment-mean + einsum + root + bias + BN partials ----------------
// Block: 256 threads, 64-node tile. acc: 8 nodes x 4 cols per thread.

template <int F>
__launch_bounds__(256)
__global__ void rgcn_layer(const float* __restrict__ xin, const float* __restrict__ Wrel,
                           const float* __restrict__ root, const float* __restrict__ bias,
                           const int* __restrict__ off, const int* __restrict__ csr,
                           float* __restrict__ out, float* __restrict__ bn_sum,
                           float* __restrict__ bn_sq) {
    constexpr int TN = 64;
    __shared__ float A[TN * F];
    const int t = threadIdx.x;
    const int n0 = blockIdx.x * TN;
    const int og = t & 31;       // output group: 4 consecutive columns
    const int gi = t >> 5;       // node group: 8 nodes
    const int o4 = og * 4;

    float acc[8][4];
#pragma unroll
    for (int i = 0; i < 8; ++i)
#pragma unroll
        for (int c = 0; c < 4; ++c) acc[i][c] = 0.f;

    constexpr int NPG = (F == 64) ? 16 : 32;  // nodes per staging group
    const int feat = t & (F - 1);
    const int sgrp = t / F;

    for (int rel = 0; rel <= NREL; ++rel) {
        // ---- stage A tile: segment means for this relation (or self features for root) ----
        for (int j = 0; j < NPG; ++j) {
            int nl = sgrp * NPG + j;
            int n = n0 + nl;
            float v = 0.f;
            if (n < N_NODES) {
                if (rel < NREL) {
                    int s = n * NREL + rel;
                    int e0 = off[s], e1 = off[s + 1];
                    for (int e = e0; e < e1; ++e) v += xin[csr[e] * F + feat];
                    if (e1 > e0) v *= (1.0f / (float)(e1 - e0));
                } else {
                    v = xin[n * F + feat];
                }
            }
            A[nl * F + feat] = v;
        }
        __syncthreads();
        // ---- accumulate GEMM partial ----
        const float* W = (rel < NREL) ? (Wrel + (size_t)rel * F * HID) : root;
        for (int k = 0; k < F; ++k) {
            const float4 w = *reinterpret_cast<const float4*>(W + k * HID + o4);
#pragma unroll
            for (int i = 0; i < 8; ++i) {
                float a = A[(gi * 8 + i) * F + k];
                acc[i][0] += a * w.x;
                acc[i][1] += a * w.y;
                acc[i][2] += a * w.z;
                acc[i][3] += a * w.w;
            }
        }
        __syncthreads();
    }

    // ---- epilogue: bias, store, BN partial stats ----
    const float4 bv = *reinterpret_cast<const float4*>(bias + o4);
    float ps[4] = {0, 0, 0, 0}, pq[4] = {0, 0, 0, 0};
#pragma unroll
    for (int i = 0; i < 8; ++i) {
        int n = n0 + gi * 8 + i;
        if (n < N_NODES) {
            float4 o;
            o.x = acc[i][0] + bv.x;
            o.y = acc[i][1] + bv.y;
            o.z = acc[i][2] + bv.z;
            o.w = acc[i][3] + bv.w;
            *reinterpret_cast<float4*>(out + (size_t)n * HID + o4) = o;
            ps[0] += o.x; ps[1] += o.y; ps[2] += o.z; ps[3] += o.w;
            pq[0] += o.x * o.x; pq[1] += o.y * o.y; pq[2] += o.z * o.z; pq[3] += o.w * o.w;
        }
    }
#pragma unroll
    for (int c = 0; c < 4; ++c) {
        ps[c] += __shfl_xor(ps[c], 32);
        pq[c] += __shfl_xor(pq[c], 32);
    }
    float* RED = A;  // reuse LDS (>= 4*256 floats)
    const int lane = t & 63;
    const int wid = t >> 6;
    if (lane < 32) {
#pragma unroll
        for (int c = 0; c < 4; ++c) {
            RED[wid * 256 + lane * 8 + c] = ps[c];
            RED[wid * 256 + lane * 8 + 4 + c] = pq[c];
        }
    }
    __syncthreads();
    {
        int og2 = t & 31, idx = t >> 5;
        float v = RED[0 * 256 + og2 * 8 + idx] + RED[1 * 256 + og2 * 8 + idx] +
                  RED[2 * 256 + og2 * 8 + idx] + RED[3 * 256 + og2 * 8 + idx];
        if (idx < 4)
            atomicAdd(&bn_sum[og2 * 4 + idx], v);
        else
            atomicAdd(&bn_sq[og2 * 4 + (idx - 4)], v);
    }
}

// ---------------- BN finalize + apply ----------------

__global__ void bn_finalize(const float* __restrict__ bn_sum, const float* __restrict__ bn_sq,
                            const float* __restrict__ gamma, const float* __restrict__ beta,
                            float* __restrict__ coefA, float* __restrict__ coefB) {
    int o = threadIdx.x;
    if (o < HID) {
        float mu = bn_sum[o] / (float)N_NODES;
        float var = bn_sq[o] / (float)N_NODES - mu * mu;
        float a = gamma[o] / sqrtf(var + BN_EPS);
        coefA[o] = a;
        coefB[o] = beta[o] - a * mu;
    }
}

__global__ void bn_relu(float* __restrict__ h, const float* __restrict__ cA,
                        const float* __restrict__ cB) {
    int i = blockIdx.x * blockDim.x + threadIdx.x;  // float4 index
    constexpr int TOTAL = N_NODES * HID / 4;
    if (i < TOTAL) {
        int o4 = i & 31;
        float4 a = reinterpret_cast<const float4*>(cA)[o4];
        float4 b = reinterpret_cast<const float4*>(cB)[o4];
        float4 v = reinterpret_cast<float4*>(h)[i];
        v.x = fmaxf(a.x * v.x + b.x, 0.f);
        v.y = fmaxf(a.y * v.y + b.y, 0.f);
        v.z = fmaxf(a.z * v.z + b.z, 0.f);
        v.w = fmaxf(a.w * v.w + b.w, 0.f);
        reinterpret_cast<float4*>(h)[i] = v;
    }
}

// ---------------- pooling + head ----------------

__global__ void pool_kernel(const float* __restrict__ h, const int* __restrict__ batch,
                            float* __restrict__ psum, float* __restrict__ pcnt) {
    int i = blockIdx.x * blockDim.x + threadIdx.x;
    if (i < N_NODES * HID) {
        int n = i >> 7, o = i & 127;
        int g = batch[n];
        atomicAdd(&psum[g * HID + o], h[i]);
        if (o == 0) atomicAdd(&pcnt[g], 1.0f);
    }
}

__global__ void final_kernel(const float* __restrict__ psum, const float* __restrict__ pcnt,
                             const float* __restrict__ Wf, const float* __restrict__ bf,
                             float* __restrict__ out) {
    __shared__ float p[HID];
    int g = blockIdx.x, t = threadIdx.x;  // 64 threads
    float inv = 1.0f / fmaxf(pcnt[g], 1.0f);
    p[t] = psum[g * HID + t] * inv;
    p[t + 64] = psum[g * HID + t + 64] * inv;
    __syncthreads();
    if (t < NCLS) {
        float s = bf[t];
#pragma unroll 16
        for (int k = 0; k < HID; ++k) s += p[k] * Wf[k * NCLS + t];
        out[g * NCLS + t] = s;
    }
}

// ---------------- launch ----------------

extern "C" void kernel_launch(void* const* d_in, const int* in_sizes, int n_in,
                              void* d_out, int out_size, void* d_ws, size_t ws_size,
                              hipStream_t stream) {
    const float* x      = (const float*)d_in[0];
    const float* Wrel1  = (const float*)d_in[1];
    const float* root1  = (const float*)d_in[2];
    const float* bias1  = (const float*)d_in[3];
    const float* gamma1 = (const float*)d_in[4];
    const float* beta1  = (const float*)d_in[5];
    const float* Wrel2  = (const float*)d_in[6];
    const float* root2  = (const float*)d_in[7];
    const float* bias2  = (const float*)d_in[8];
    const float* gamma2 = (const float*)d_in[9];
    const float* beta2  = (const float*)d_in[10];
    const float* Wf     = (const float*)d_in[11];
    const float* bf     = (const float*)d_in[12];
    const int* ei       = (const int*)d_in[13];
    const int* et       = (const int*)d_in[14];
    const int* batch    = (const int*)d_in[15];
    const int* srcv = ei;
    const int* dstv = ei + N_EDGES;

    char* w = (char*)d_ws;
    auto alloc = [&](size_t bytes) -> char* {
        char* p = w;
        w += (bytes + 255) / 256 * 256;
        return p;
    };
    int* cnt    = (int*)alloc((size_t)NSEG * 4);
    int* off    = (int*)alloc((size_t)(NSEG + 1) * 4);
    int* cursor = (int*)alloc((size_t)NSEG * 4);
    int* csr    = (int*)alloc((size_t)N_EDGES * 4);
    int* csum   = (int*)alloc((size_t)NCHUNK * 4);
    int* coff   = (int*)alloc((size_t)NCHUNK * 4);
    float* H1   = (float*)alloc((size_t)N_NODES * HID * 4);
    float* H2   = (float*)alloc((size_t)N_NODES * HID * 4);
    float* bn1  = (float*)alloc(4 * HID * 4);  // sum | sq | coefA | coefB
    float* bn2  = (float*)alloc(4 * HID * 4);
    float* psum = (float*)alloc((size_t)NGRAPH * HID * 4);
    float* pcnt = (float*)alloc((size_t)NGRAPH * 4);

    hipMemsetAsync(cnt, 0, (size_t)NSEG * 4, stream);
    hipMemsetAsync(bn1, 0, 2 * HID * 4, stream);
    hipMemsetAsync(bn2, 0, 2 * HID * 4, stream);
    hipMemsetAsync(psum, 0, (size_t)NGRAPH * HID * 4, stream);
    hipMemsetAsync(pcnt, 0, (size_t)NGRAPH * 4, stream);

    count_edges<<<(N_EDGES + 255) / 256, 256, 0, stream>>>(dstv, et, cnt);
    scan_a<<<NCHUNK, 256, 0, stream>>>(cnt, csum);
    scan_b<<<1, 1024, 0, stream>>>(csum, coff);
    scan_c<<<NCHUNK, 256, 0, stream>>>(cnt, coff, off, cursor);
    fill_csr<<<(N_EDGES + 255) / 256, 256, 0, stream>>>(srcv, dstv, et, cursor, csr);

    int nblk = (N_NODES + 63) / 64;  // 782
    rgcn_layer<64><<<nblk, 256, 0, stream>>>(x, Wrel1, root1, bias1, off, csr, H1, bn1, bn1 + HID);
    bn_finalize<<<1, 128, 0, stream>>>(bn1, bn1 + HID, gamma1, beta1, bn1 + 2 * HID, bn1 + 3 * HID);
    bn_relu<<<(N_NODES * HID / 4 + 255) / 256, 256, 0, stream>>>(H1, bn1 + 2 * HID, bn1 + 3 * HID);

    rgcn_layer<128><<<nblk, 256, 0, stream>>>(H1, Wrel2, root2, bias2, off, csr, H2, bn2, bn2 + HID);
    bn_finalize<<<1, 128, 0, stream>>>(bn2, bn2 + HID, gamma2, beta2, bn2 + 2 * HID, bn2 + 3 * HID);
    bn_relu<<<(N_NODES * HID / 4 + 255) / 256, 256, 0, stream>>>(H2, bn2 + 2 * HID, bn2 + 3 * HID);

    pool_kernel<<<(N_NODES * HID + 255) / 256, 256, 0, stream>>>(H2, batch, psum, pcnt);
    final_kernel<<<NGRAPH, 64, 0, stream>>>(psum, pcnt, Wf, bf, (float*)d_out);
}

// Round 2
// 1105.544 us; speedup vs baseline: 1.9925x; 1.9925x over previous
//
#include <hip/hip_runtime.h>

constexpr int N_NODES = 50000;
constexpr int N_EDGES = 1600000;
constexpr int NREL    = 12;
constexpr int F_INPUT = 64;
constexpr int HID     = 128;
constexpr int NCLS    = 10;
constexpr int NGRAPH  = 256;
constexpr int NSEG    = N_NODES * NREL;       // 600000
constexpr int CHUNK   = 1024;
constexpr int NCHUNK  = (NSEG + CHUNK - 1) / CHUNK;  // 586
constexpr float BN_EPS = 1e-5f;

// ---------------- CSR build ----------------

__global__ void count_edges(const int* __restrict__ dst, const int* __restrict__ et,
                            int* __restrict__ cnt) {
    int e = blockIdx.x * blockDim.x + threadIdx.x;
    if (e < N_EDGES) atomicAdd(&cnt[dst[e] * NREL + et[e]], 1);
}

__global__ void scan_a(const int* __restrict__ cnt, int* __restrict__ csum) {
    __shared__ int red[256];
    int b = blockIdx.x, t = threadIdx.x;
    int base = b * CHUNK + t * 4;
    int s = 0;
#pragma unroll
    for (int j = 0; j < 4; ++j) {
        int i = base + j;
        if (i < NSEG) s += cnt[i];
    }
    red[t] = s;
    __syncthreads();
    for (int d = 128; d > 0; d >>= 1) {
        if (t < d) red[t] += red[t + d];
        __syncthreads();
    }
    if (t == 0) csum[b] = red[0];
}

__global__ void scan_b(const int* __restrict__ csum, int* __restrict__ coff) {
    __shared__ int s[1024];
    int t = threadIdx.x;
    s[t] = (t < NCHUNK) ? csum[t] : 0;
    __syncthreads();
    for (int d = 1; d < 1024; d <<= 1) {
        int v = (t >= d) ? s[t - d] : 0;
        __syncthreads();
        s[t] += v;
        __syncthreads();
    }
    if (t < NCHUNK) coff[t] = (t == 0) ? 0 : s[t - 1];
}

__global__ void scan_c(const int* __restrict__ cnt, const int* __restrict__ coff,
                       int* __restrict__ off, int* __restrict__ cursor) {
    __shared__ int ts[256];
    int b = blockIdx.x, t = threadIdx.x;
    int base = b * CHUNK + t * 4;
    int c[4];
    int s = 0;
#pragma unroll
    for (int j = 0; j < 4; ++j) {
        int i = base + j;
        c[j] = (i < NSEG) ? cnt[i] : 0;
        s += c[j];
    }
    ts[t] = s;
    __syncthreads();
    for (int d = 1; d < 256; d <<= 1) {
        int v = (t >= d) ? ts[t - d] : 0;
        __syncthreads();
        ts[t] += v;
        __syncthreads();
    }
    int run = coff[b] + ((t == 0) ? 0 : ts[t - 1]);
#pragma unroll
    for (int j = 0; j < 4; ++j) {
        int i = base + j;
        if (i < NSEG) {
            off[i] = run;
            cursor[i] = run;
            run += c[j];
        }
    }
    if (b == 0 && t == 0) off[NSEG] = N_EDGES;
}

__global__ void fill_csr(const int* __restrict__ src, const int* __restrict__ dst,
                         const int* __restrict__ et, int* __restrict__ cursor,
                         int* __restrict__ csr_src) {
    int e = blockIdx.x * blockDim.x + threadIdx.x;
    if (e < N_EDGES) {
        int s = dst[e] * NREL + et[e];
        int p = atomicAdd(&cursor[s], 1);
        csr_src[p] = src[e];
    }
}

// ---------------- fused RGCN layer ----------------
// Block: 256 threads, 64-node tile.
// Staging: 4 threads per node; each thread accumulates F/4 features (F/16
// float4s) of the node's segment-mean in registers over the edge list,
// normalizes, writes to LDS once. Serial chain depth = avg 2.67 edges,
// all gathers independent float4s.
// GEMM: register-blocked 8 nodes x 4 cols per thread over the LDS A-tile.

template <int F>
__launch_bounds__(256)
__global__ void rgcn_layer(const float* __restrict__ xin, const float* __restrict__ Wrel,
                           const float* __restrict__ root, const float* __restrict__ bias,
                           const int* __restrict__ off, const int* __restrict__ csr,
                           float* __restrict__ out, float* __restrict__ bn_sum,
                           float* __restrict__ bn_sq) {
    constexpr int TN = 64;
    constexpr int FP = F + 4;          // padded row (floats) to spread LDS banks
    constexpr int CH = F / 16;         // float4 chunks per staging thread
    __shared__ float A[TN * FP];
    const int t = threadIdx.x;
    const int n0 = blockIdx.x * TN;
    const int og = t & 31;       // output group: 4 consecutive columns
    const int gi = t >> 5;       // node group: 8 nodes
    const int o4 = og * 4;

    const int nl   = t >> 2;     // staging: node within tile (0..63)
    const int tid4 = t & 3;      // staging: quarter-row lane

    float acc[8][4];
#pragma unroll
    for (int i = 0; i < 8; ++i)
#pragma unroll
        for (int c = 0; c < 4; ++c) acc[i][c] = 0.f;

    for (int rel = 0; rel <= NREL; ++rel) {
        // ---- stage A tile: segment means (or self features for root term) ----
        float4 a4[CH];
#pragma unroll
        for (int c = 0; c < CH; ++c) a4[c] = make_float4(0.f, 0.f, 0.f, 0.f);
        {
            int n = n0 + nl;
            if (n < N_NODES) {
                if (rel < NREL) {
                    int s = n * NREL + rel;
                    int e0 = off[s], e1 = off[s + 1];
                    for (int e = e0; e < e1; ++e) {
                        const float4* row =
                            reinterpret_cast<const float4*>(xin + (size_t)csr[e] * F);
#pragma unroll
                        for (int c = 0; c < CH; ++c) {
                            float4 v = row[c * 4 + tid4];
                            a4[c].x += v.x; a4[c].y += v.y; a4[c].z += v.z; a4[c].w += v.w;
                        }
                    }
                    if (e1 > e0) {
                        float inv = 1.0f / (float)(e1 - e0);
#pragma unroll
                        for (int c = 0; c < CH; ++c) {
                            a4[c].x *= inv; a4[c].y *= inv; a4[c].z *= inv; a4[c].w *= inv;
                        }
                    }
                } else {
                    const float4* row = reinterpret_cast<const float4*>(xin + (size_t)n * F);
#pragma unroll
                    for (int c = 0; c < CH; ++c) a4[c] = row[c * 4 + tid4];
                }
            }
        }
        {
            float* Arow = A + nl * FP;
#pragma unroll
            for (int c = 0; c < CH; ++c)
                *reinterpret_cast<float4*>(Arow + (c * 4 + tid4) * 4) = a4[c];
        }
        __syncthreads();
        // ---- accumulate GEMM partial ----
        const float* W = (rel < NREL) ? (Wrel + (size_t)rel * F * HID) : root;
        for (int k = 0; k < F; ++k) {
            const float4 w = *reinterpret_cast<const float4*>(W + k * HID + o4);
#pragma unroll
            for (int i = 0; i < 8; ++i) {
                float a = A[(gi * 8 + i) * FP + k];
                acc[i][0] += a * w.x;
                acc[i][1] += a * w.y;
                acc[i][2] += a * w.z;
                acc[i][3] += a * w.w;
            }
        }
        __syncthreads();
    }

    // ---- epilogue: bias, store, BN partial stats ----
    const float4 bv = *reinterpret_cast<const float4*>(bias + o4);
    float ps[4] = {0, 0, 0, 0}, pq[4] = {0, 0, 0, 0};
#pragma unroll
    for (int i = 0; i < 8; ++i) {
        int n = n0 + gi * 8 + i;
        if (n < N_NODES) {
            float4 o;
            o.x = acc[i][0] + bv.x;
            o.y = acc[i][1] + bv.y;
            o.z = acc[i][2] + bv.z;
            o.w = acc[i][3] + bv.w;
            *reinterpret_cast<float4*>(out + (size_t)n * HID + o4) = o;
            ps[0] += o.x; ps[1] += o.y; ps[2] += o.z; ps[3] += o.w;
            pq[0] += o.x * o.x; pq[1] += o.y * o.y; pq[2] += o.z * o.z; pq[3] += o.w * o.w;
        }
    }
#pragma unroll
    for (int c = 0; c < 4; ++c) {
        ps[c] += __shfl_xor(ps[c], 32);
        pq[c] += __shfl_xor(pq[c], 32);
    }
    float* RED = A;  // reuse LDS (>= 4*256 floats)
    const int lane = t & 63;
    const int wid = t >> 6;
    __syncthreads();
    if (lane < 32) {
#pragma unroll
        for (int c = 0; c < 4; ++c) {
            RED[wid * 256 + lane * 8 + c] = ps[c];
            RED[wid * 256 + lane * 8 + 4 + c] = pq[c];
        }
    }
    __syncthreads();
    {
        int og2 = t & 31, idx = t >> 5;
        float v = RED[0 * 256 + og2 * 8 + idx] + RED[1 * 256 + og2 * 8 + idx] +
                  RED[2 * 256 + og2 * 8 + idx] + RED[3 * 256 + og2 * 8 + idx];
        if (idx < 4)
            atomicAdd(&bn_sum[og2 * 4 + idx], v);
        else
            atomicAdd(&bn_sq[og2 * 4 + (idx - 4)], v);
    }
}

// ---------------- BN finalize + apply ----------------

__global__ void bn_finalize(const float* __restrict__ bn_sum, const float* __restrict__ bn_sq,
                            const float* __restrict__ gamma, const float* __restrict__ beta,
                            float* __restrict__ coefA, float* __restrict__ coefB) {
    int o = threadIdx.x;
    if (o < HID) {
        float mu = bn_sum[o] / (float)N_NODES;
        float var = bn_sq[o] / (float)N_NODES - mu * mu;
        float a = gamma[o] / sqrtf(var + BN_EPS);
        coefA[o] = a;
        coefB[o] = beta[o] - a * mu;
    }
}

__global__ void bn_relu(float* __restrict__ h, const float* __restrict__ cA,
                        const float* __restrict__ cB) {
    int i = blockIdx.x * blockDim.x + threadIdx.x;  // float4 index
    constexpr int TOTAL = N_NODES * HID / 4;
    if (i < TOTAL) {
        int o4 = i & 31;
        float4 a = reinterpret_cast<const float4*>(cA)[o4];
        float4 b = reinterpret_cast<const float4*>(cB)[o4];
        float4 v = reinterpret_cast<float4*>(h)[i];
        v.x = fmaxf(a.x * v.x + b.x, 0.f);
        v.y = fmaxf(a.y * v.y + b.y, 0.f);
        v.z = fmaxf(a.z * v.z + b.z, 0.f);
        v.w = fmaxf(a.w * v.w + b.w, 0.f);
        reinterpret_cast<float4*>(h)[i] = v;
    }
}

// ---------------- pooling + head ----------------

__global__ void pool_kernel(const float* __restrict__ h, const int* __restrict__ batch,
                            float* __restrict__ psum, float* __restrict__ pcnt) {
    int i = blockIdx.x * blockDim.x + threadIdx.x;
    if (i < N_NODES * HID) {
        int n = i >> 7, o = i & 127;
        int g = batch[n];
        atomicAdd(&psum[g * HID + o], h[i]);
        if (o == 0) atomicAdd(&pcnt[g], 1.0f);
    }
}

__global__ void final_kernel(const float* __restrict__ psum, const float* __restrict__ pcnt,
                             const float* __restrict__ Wf, const float* __restrict__ bf,
                             float* __restrict__ out) {
    __shared__ float p[HID];
    int g = blockIdx.x, t = threadIdx.x;  // 64 threads
    float inv = 1.0f / fmaxf(pcnt[g], 1.0f);
    p[t] = psum[g * HID + t] * inv;
    p[t + 64] = psum[g * HID + t + 64] * inv;
    __syncthreads();
    if (t < NCLS) {
        float s = bf[t];
#pragma unroll 16
        for (int k = 0; k < HID; ++k) s += p[k] * Wf[k * NCLS + t];
        out[g * NCLS + t] = s;
    }
}

// ---------------- launch ----------------

extern "C" void kernel_launch(void* const* d_in, const int* in_sizes, int n_in,
                              void* d_out, int out_size, void* d_ws, size_t ws_size,
                              hipStream_t stream) {
    const float* x      = (const float*)d_in[0];
    const float* Wrel1  = (const float*)d_in[1];
    const float* root1  = (const float*)d_in[2];
    const float* bias1  = (const float*)d_in[3];
    const float* gamma1 = (const float*)d_in[4];
    const float* beta1  = (const float*)d_in[5];
    const float* Wrel2  = (const float*)d_in[6];
    const float* root2  = (const float*)d_in[7];
    const float* bias2  = (const float*)d_in[8];
    const float* gamma2 = (const float*)d_in[9];
    const float* beta2  = (const float*)d_in[10];
    const float* Wf     = (const float*)d_in[11];
    const float* bf     = (const float*)d_in[12];
    const int* ei       = (const int*)d_in[13];
    const int* et       = (const int*)d_in[14];
    const int* batch    = (const int*)d_in[15];
    const int* srcv = ei;
    const int* dstv = ei + N_EDGES;

    char* w = (char*)d_ws;
    auto alloc = [&](size_t bytes) -> char* {
        char* p = w;
        w += (bytes + 255) / 256 * 256;
        return p;
    };
    int* cnt    = (int*)alloc((size_t)NSEG * 4);
    int* off    = (int*)alloc((size_t)(NSEG + 1) * 4);
    int* cursor = (int*)alloc((size_t)NSEG * 4);
    int* csr    = (int*)alloc((size_t)N_EDGES * 4);
    int* csum   = (int*)alloc((size_t)NCHUNK * 4);
    int* coff   = (int*)alloc((size_t)NCHUNK * 4);
    float* H1   = (float*)alloc((size_t)N_NODES * HID * 4);
    float* H2   = (float*)alloc((size_t)N_NODES * HID * 4);
    float* bn1  = (float*)alloc(4 * HID * 4);  // sum | sq | coefA | coefB
    float* bn2  = (float*)alloc(4 * HID * 4);
    float* psum = (float*)alloc((size_t)NGRAPH * HID * 4);
    float* pcnt = (float*)alloc((size_t)NGRAPH * 4);

    hipMemsetAsync(cnt, 0, (size_t)NSEG * 4, stream);
    hipMemsetAsync(bn1, 0, 2 * HID * 4, stream);
    hipMemsetAsync(bn2, 0, 2 * HID * 4, stream);
    hipMemsetAsync(psum, 0, (size_t)NGRAPH * HID * 4, stream);
    hipMemsetAsync(pcnt, 0, (size_t)NGRAPH * 4, stream);

    count_edges<<<(N_EDGES + 255) / 256, 256, 0, stream>>>(dstv, et, cnt);
    scan_a<<<NCHUNK, 256, 0, stream>>>(cnt, csum);
    scan_b<<<1, 1024, 0, stream>>>(csum, coff);
    scan_c<<<NCHUNK, 256, 0, stream>>>(cnt, coff, off, cursor);
    fill_csr<<<(N_EDGES + 255) / 256, 256, 0, stream>>>(srcv, dstv, et, cursor, csr);

    int nblk = (N_NODES + 63) / 64;  // 782
    rgcn_layer<64><<<nblk, 256, 0, stream>>>(x, Wrel1, root1, bias1, off, csr, H1, bn1, bn1 + HID);
    bn_finalize<<<1, 128, 0, stream>>>(bn1, bn1 + HID, gamma1, beta1, bn1 + 2 * HID, bn1 + 3 * HID);
    bn_relu<<<(N_NODES * HID / 4 + 255) / 256, 256, 0, stream>>>(H1, bn1 + 2 * HID, bn1 + 3 * HID);

    rgcn_layer<128><<<nblk, 256, 0, stream>>>(H1, Wrel2, root2, bias2, off, csr, H2, bn2, bn2 + HID);
    bn_finalize<<<1, 128, 0, stream>>>(bn2, bn2 + HID, gamma2, beta2, bn2 + 2 * HID, bn2 + 3 * HID);
    bn_relu<<<(N_NODES * HID / 4 + 255) / 256, 256, 0, stream>>>(H2, bn2 + 2 * HID, bn2 + 3 * HID);

    pool_kernel<<<(N_NODES * HID + 255) / 256, 256, 0, stream>>>(H2, batch, psum, pcnt);
    final_kernel<<<NGRAPH, 64, 0, stream>>>(psum, pcnt, Wf, bf, (float*)d_out);
}

// Round 3
// 689.244 us; speedup vs baseline: 3.1960x; 1.6040x over previous
//
#include <hip/hip_runtime.h>

constexpr int N_NODES = 50000;
constexpr int N_EDGES = 1600000;
constexpr int NREL    = 12;
constexpr int F_INPUT = 64;
constexpr int HID     = 128;
constexpr int NCLS    = 10;
constexpr int NGRAPH  = 256;
constexpr int NSEG    = N_NODES * NREL;       // 600000
constexpr int CHUNK   = 1024;
constexpr int NCHUNK  = (NSEG + CHUNK - 1) / CHUNK;  // 586
constexpr float BN_EPS = 1e-5f;

typedef float v4f __attribute__((ext_vector_type(4)));
typedef short s8b __attribute__((ext_vector_type(8)));

__device__ __forceinline__ unsigned f2bf(float f) {
    unsigned u = __float_as_uint(f);
    return (u + 0x7FFFu + ((u >> 16) & 1u)) >> 16;   // RNE fp32->bf16
}
__device__ __forceinline__ unsigned pack2(float a, float b) {
    return f2bf(a) | (f2bf(b) << 16);
}

// ---------------- CSR build ----------------

__global__ void count_edges(const int* __restrict__ dst, const int* __restrict__ et,
                            int* __restrict__ cnt) {
    int e = blockIdx.x * blockDim.x + threadIdx.x;
    if (e < N_EDGES) atomicAdd(&cnt[dst[e] * NREL + et[e]], 1);
}

__global__ void scan_a(const int* __restrict__ cnt, int* __restrict__ csum) {
    __shared__ int red[256];
    int b = blockIdx.x, t = threadIdx.x;
    int base = b * CHUNK + t * 4;
    int s = 0;
#pragma unroll
    for (int j = 0; j < 4; ++j) {
        int i = base + j;
        if (i < NSEG) s += cnt[i];
    }
    red[t] = s;
    __syncthreads();
    for (int d = 128; d > 0; d >>= 1) {
        if (t < d) red[t] += red[t + d];
        __syncthreads();
    }
    if (t == 0) csum[b] = red[0];
}

__global__ void scan_b(const int* __restrict__ csum, int* __restrict__ coff) {
    __shared__ int s[1024];
    int t = threadIdx.x;
    s[t] = (t < NCHUNK) ? csum[t] : 0;
    __syncthreads();
    for (int d = 1; d < 1024; d <<= 1) {
        int v = (t >= d) ? s[t - d] : 0;
        __syncthreads();
        s[t] += v;
        __syncthreads();
    }
    if (t < NCHUNK) coff[t] = (t == 0) ? 0 : s[t - 1];
}

__global__ void scan_c(const int* __restrict__ cnt, const int* __restrict__ coff,
                       int* __restrict__ off, int* __restrict__ cursor) {
    __shared__ int ts[256];
    int b = blockIdx.x, t = threadIdx.x;
    int base = b * CHUNK + t * 4;
    int c[4];
    int s = 0;
#pragma unroll
    for (int j = 0; j < 4; ++j) {
        int i = base + j;
        c[j] = (i < NSEG) ? cnt[i] : 0;
        s += c[j];
    }
    ts[t] = s;
    __syncthreads();
    for (int d = 1; d < 256; d <<= 1) {
        int v = (t >= d) ? ts[t - d] : 0;
        __syncthreads();
        ts[t] += v;
        __syncthreads();
    }
    int run = coff[b] + ((t == 0) ? 0 : ts[t - 1]);
#pragma unroll
    for (int j = 0; j < 4; ++j) {
        int i = base + j;
        if (i < NSEG) {
            off[i] = run;
            cursor[i] = run;
            run += c[j];
        }
    }
    if (b == 0 && t == 0) off[NSEG] = N_EDGES;
}

__global__ void fill_csr(const int* __restrict__ src, const int* __restrict__ dst,
                         const int* __restrict__ et, int* __restrict__ cursor,
                         int* __restrict__ csr_src) {
    int e = blockIdx.x * blockDim.x + threadIdx.x;
    if (e < N_EDGES) {
        int s = dst[e] * NREL + et[e];
        int p = atomicAdd(&cursor[s], 1);
        csr_src[p] = src[e];
    }
}

// ---------------- weight pack: fp32 [r][k][n] -> bf16 B-fragment layout ----------------
// Wp[((r*KB + k/32)*HID + n)*32 + k%32]; r==12 is the root matrix.

__global__ void pack_w(const float* __restrict__ Wrel, const float* __restrict__ root,
                       ushort* __restrict__ Wp, int F) {
    int idx = blockIdx.x * 256 + threadIdx.x;
    int tot = 13 * F * HID;
    if (idx >= tot) return;
    int r = idx / (F * HID);
    int rem = idx - r * F * HID;
    int k = rem / HID;
    int n = rem - k * HID;
    const float* W = (r < NREL) ? (Wrel + (size_t)r * F * HID) : root;
    float v = W[k * HID + n];
    int b = k >> 5, kk = k & 31;
    Wp[(((size_t)(r * (F / 32) + b)) * HID + n) * 32 + kk] = (ushort)f2bf(v);
}

__global__ void to_bf16(const float* __restrict__ in, ushort* __restrict__ out, int n4) {
    int i = blockIdx.x * 256 + threadIdx.x;
    if (i < n4) {
        float4 v = reinterpret_cast<const float4*>(in)[i];
        uint2 o;
        o.x = pack2(v.x, v.y);
        o.y = pack2(v.z, v.w);
        reinterpret_cast<uint2*>(out)[i] = o;
    }
}

// ---------------- fused RGCN layer (MFMA) ----------------
// Block 256 (4 waves), 64-node tile. Stage bf16 segment-means into LDS
// (A-fragment row-major, +8 bf16 pad), MFMA 16x16x32 against pre-packed
// bf16 weights (B frags straight from L2-resident global). fp32 epilogue:
// bias + store + BN partial stats.

template <int F>
__launch_bounds__(256)
__global__ void rgcn_mfma(const ushort* __restrict__ xin, const ushort* __restrict__ Wp,
                          const float* __restrict__ bias,
                          const int* __restrict__ off, const int* __restrict__ csr,
                          float* __restrict__ out, float* __restrict__ bn_sum,
                          float* __restrict__ bn_sq) {
    constexpr int TN  = 64;
    constexpr int FP2 = F + 8;      // padded LDS row (bf16 elems)
    constexpr int F4  = F / 4;      // staged elems per thread
    constexpr int NLD = F4 / 8;     // 16B chunks per staging thread
    constexpr int KB  = F / 32;     // K-blocks per relation
    __shared__ __align__(16) ushort A[TN * FP2];

    const int t = threadIdx.x;
    const int n0 = blockIdx.x * TN;
    const int nl = t >> 2, tid4 = t & 3;
    const int lane = t & 63, wave = t >> 6, q = lane >> 4, l16 = lane & 15;

    v4f acc[8];
#pragma unroll
    for (int nt = 0; nt < 8; ++nt) acc[nt] = (v4f){0.f, 0.f, 0.f, 0.f};

    const int nglob = n0 + nl;
    uint4* Aw = reinterpret_cast<uint4*>(A + nl * FP2 + tid4 * F4);
    const ushort* Arow = A + (wave * 16 + l16) * FP2;

    for (int rel = 0; rel <= NREL; ++rel) {
        // ---- stage A tile ----
        if (rel < NREL) {
            float accs[F4];
#pragma unroll
            for (int i = 0; i < F4; ++i) accs[i] = 0.f;
            int cntE = 0;
            if (nglob < N_NODES) {
                int s = nglob * NREL + rel;
                int e0 = off[s], e1 = off[s + 1];
                cntE = e1 - e0;
                for (int e = e0; e < e1; ++e) {
                    const uint4* row = reinterpret_cast<const uint4*>(
                        xin + (size_t)csr[e] * F + tid4 * F4);
#pragma unroll
                    for (int c = 0; c < NLD; ++c) {
                        uint4 u = row[c];
                        accs[c * 8 + 0] += __uint_as_float(u.x << 16);
                        accs[c * 8 + 1] += __uint_as_float(u.x & 0xFFFF0000u);
                        accs[c * 8 + 2] += __uint_as_float(u.y << 16);
                        accs[c * 8 + 3] += __uint_as_float(u.y & 0xFFFF0000u);
                        accs[c * 8 + 4] += __uint_as_float(u.z << 16);
                        accs[c * 8 + 5] += __uint_as_float(u.z & 0xFFFF0000u);
                        accs[c * 8 + 6] += __uint_as_float(u.w << 16);
                        accs[c * 8 + 7] += __uint_as_float(u.w & 0xFFFF0000u);
                    }
                }
            }
            float inv = (cntE > 0) ? 1.0f / (float)cntE : 0.f;
#pragma unroll
            for (int c = 0; c < NLD; ++c) {
                uint4 o;
                o.x = pack2(accs[c * 8 + 0] * inv, accs[c * 8 + 1] * inv);
                o.y = pack2(accs[c * 8 + 2] * inv, accs[c * 8 + 3] * inv);
                o.z = pack2(accs[c * 8 + 4] * inv, accs[c * 8 + 5] * inv);
                o.w = pack2(accs[c * 8 + 6] * inv, accs[c * 8 + 7] * inv);
                Aw[c] = o;
            }
        } else {  // root term: own features, already bf16
            if (nglob < N_NODES) {
                const uint4* row = reinterpret_cast<const uint4*>(
                    xin + (size_t)nglob * F + tid4 * F4);
#pragma unroll
                for (int c = 0; c < NLD; ++c) Aw[c] = row[c];
            } else {
                uint4 z = make_uint4(0, 0, 0, 0);
#pragma unroll
                for (int c = 0; c < NLD; ++c) Aw[c] = z;
            }
        }
        __syncthreads();
        // ---- MFMA accumulate ----
#pragma unroll
        for (int b = 0; b < KB; ++b) {
            s8b af = *reinterpret_cast<const s8b*>(Arow + b * 32 + q * 8);
            const ushort* wbase =
                Wp + ((size_t)(rel * KB + b) * HID + l16) * 32 + q * 8;
#pragma unroll
            for (int nt = 0; nt < 8; ++nt) {
                s8b bfb = *reinterpret_cast<const s8b*>(wbase + (size_t)nt * 16 * 32);
                acc[nt] = __builtin_amdgcn_mfma_f32_16x16x32_bf16(af, bfb, acc[nt], 0, 0, 0);
            }
        }
        __syncthreads();
    }

    // ---- epilogue: bias + store + BN partials ----
    float* RED = reinterpret_cast<float*>(A);  // A no longer needed
#pragma unroll
    for (int nt = 0; nt < 8; ++nt) {
        int col = nt * 16 + l16;
        float bcol = bias[col];
        float s = 0.f, sq2 = 0.f;
#pragma unroll
        for (int r = 0; r < 4; ++r) {
            int n = n0 + wave * 16 + q * 4 + r;
            if (n < N_NODES) {
                float v = acc[nt][r] + bcol;
                out[(size_t)n * HID + col] = v;
                s += v;
                sq2 += v * v;
            }
        }
        s += __shfl_xor(s, 16);  s += __shfl_xor(s, 32);
        sq2 += __shfl_xor(sq2, 16); sq2 += __shfl_xor(sq2, 32);
        if (lane < 16) {
            RED[wave * 256 + col] = s;
            RED[wave * 256 + 128 + col] = sq2;
        }
    }
    __syncthreads();
    {
        float v = RED[0 * 256 + t] + RED[1 * 256 + t] + RED[2 * 256 + t] + RED[3 * 256 + t];
        if (t < 128)
            atomicAdd(&bn_sum[t], v);
        else
            atomicAdd(&bn_sq[t - 128], v);
    }
}

// ---------------- BN finalize / apply ----------------

__global__ void bn_finalize(const float* __restrict__ bn_sum, const float* __restrict__ bn_sq,
                            const float* __restrict__ gamma, const float* __restrict__ beta,
                            float* __restrict__ coefA, float* __restrict__ coefB) {
    int o = threadIdx.x;
    if (o < HID) {
        float mu = bn_sum[o] / (float)N_NODES;
        float var = bn_sq[o] / (float)N_NODES - mu * mu;
        float a = gamma[o] / sqrtf(var + BN_EPS);
        coefA[o] = a;
        coefB[o] = beta[o] - a * mu;
    }
}

// BN + ReLU, emit bf16 (input to next layer's gathers)
__global__ void bn_relu_bf16(const float* __restrict__ h, const float* __restrict__ cA,
                             const float* __restrict__ cB, ushort* __restrict__ outb) {
    int i = blockIdx.x * blockDim.x + threadIdx.x;  // float4 index
    constexpr int TOTAL = N_NODES * HID / 4;
    if (i < TOTAL) {
        int o4 = i & 31;
        float4 a = reinterpret_cast<const float4*>(cA)[o4];
        float4 b = reinterpret_cast<const float4*>(cB)[o4];
        float4 v = reinterpret_cast<const float4*>(h)[i];
        v.x = fmaxf(a.x * v.x + b.x, 0.f);
        v.y = fmaxf(a.y * v.y + b.y, 0.f);
        v.z = fmaxf(a.z * v.z + b.z, 0.f);
        v.w = fmaxf(a.w * v.w + b.w, 0.f);
        uint2 o;
        o.x = pack2(v.x, v.y);
        o.y = pack2(v.z, v.w);
        reinterpret_cast<uint2*>(outb)[i] = o;
    }
}

// ---------------- pooling (BN+ReLU fused; batch is sorted -> run-length) ----------------

__global__ void count_nodes(const int* __restrict__ batch, float* __restrict__ pcnt) {
    int n = blockIdx.x * 256 + threadIdx.x;
    if (n < N_NODES) atomicAdd(&pcnt[batch[n]], 1.0f);
}

__global__ void pool_bnrelu(const float* __restrict__ h, const float* __restrict__ cA,
                            const float* __restrict__ cB, const int* __restrict__ batch,
                            float* __restrict__ psum) {
    int t = threadIdx.x;
    int col = t & 127;
    int nb = blockIdx.x * 16 + (t >> 7) * 8;  // 8 consecutive nodes per thread
    float a = cA[col], b = cB[col];
    float run = 0.f;
    int curg = -1;
    for (int i = 0; i < 8; ++i) {
        int n = nb + i;
        if (n < N_NODES) {
            int g = batch[n];
            float v = fmaxf(a * h[(size_t)n * HID + col] + b, 0.f);
            if (g != curg) {
                if (curg >= 0) atomicAdd(&psum[curg * HID + col], run);
                run = 0.f;
                curg = g;
            }
            run += v;
        }
    }
    if (curg >= 0) atomicAdd(&psum[curg * HID + col], run);
}

__global__ void final_kernel(const float* __restrict__ psum, const float* __restrict__ pcnt,
                             const float* __restrict__ Wf, const float* __restrict__ bf,
                             float* __restrict__ out) {
    __shared__ float p[HID];
    int g = blockIdx.x, t = threadIdx.x;  // 64 threads
    float inv = 1.0f / fmaxf(pcnt[g], 1.0f);
    p[t] = psum[g * HID + t] * inv;
    p[t + 64] = psum[g * HID + t + 64] * inv;
    __syncthreads();
    if (t < NCLS) {
        float s = bf[t];
#pragma unroll 16
        for (int k = 0; k < HID; ++k) s += p[k] * Wf[k * NCLS + t];
        out[g * NCLS + t] = s;
    }
}

// ---------------- launch ----------------

extern "C" void kernel_launch(void* const* d_in, const int* in_sizes, int n_in,
                              void* d_out, int out_size, void* d_ws, size_t ws_size,
                              hipStream_t stream) {
    const float* x      = (const float*)d_in[0];
    const float* Wrel1  = (const float*)d_in[1];
    const float* root1  = (const float*)d_in[2];
    const float* bias1  = (const float*)d_in[3];
    const float* gamma1 = (const float*)d_in[4];
    const float* beta1  = (const float*)d_in[5];
    const float* Wrel2  = (const float*)d_in[6];
    const float* root2  = (const float*)d_in[7];
    const float* bias2  = (const float*)d_in[8];
    const float* gamma2 = (const float*)d_in[9];
    const float* beta2  = (const float*)d_in[10];
    const float* Wf     = (const float*)d_in[11];
    const float* bf     = (const float*)d_in[12];
    const int* ei       = (const int*)d_in[13];
    const int* et       = (const int*)d_in[14];
    const int* batch    = (const int*)d_in[15];
    const int* srcv = ei;
    const int* dstv = ei + N_EDGES;

    char* w = (char*)d_ws;
    auto alloc = [&](size_t bytes) -> char* {
        char* p = w;
        w += (bytes + 255) / 256 * 256;
        return p;
    };
    int* cnt     = (int*)alloc((size_t)NSEG * 4);
    int* off     = (int*)alloc((size_t)(NSEG + 1) * 4);
    int* cursor  = (int*)alloc((size_t)NSEG * 4);
    int* csr     = (int*)alloc((size_t)N_EDGES * 4);
    int* csum    = (int*)alloc((size_t)NCHUNK * 4);
    int* coff    = (int*)alloc((size_t)NCHUNK * 4);
    float* H1    = (float*)alloc((size_t)N_NODES * HID * 4);
    float* H2    = (float*)alloc((size_t)N_NODES * HID * 4);
    ushort* xb   = (ushort*)alloc((size_t)N_NODES * F_INPUT * 2);
    ushort* H1b  = (ushort*)alloc((size_t)N_NODES * HID * 2);
    ushort* Wp1  = (ushort*)alloc((size_t)13 * F_INPUT * HID * 2);
    ushort* Wp2  = (ushort*)alloc((size_t)13 * HID * HID * 2);
    float* bn1   = (float*)alloc(4 * HID * 4);  // sum | sq | coefA | coefB
    float* bn2   = (float*)alloc(4 * HID * 4);
    float* psum  = (float*)alloc((size_t)NGRAPH * HID * 4);
    float* pcnt  = (float*)alloc((size_t)NGRAPH * 4);

    hipMemsetAsync(cnt, 0, (size_t)NSEG * 4, stream);
    hipMemsetAsync(bn1, 0, 2 * HID * 4, stream);
    hipMemsetAsync(bn2, 0, 2 * HID * 4, stream);
    hipMemsetAsync(psum, 0, (size_t)NGRAPH * HID * 4, stream);
    hipMemsetAsync(pcnt, 0, (size_t)NGRAPH * 4, stream);

    // independent prep
    pack_w<<<(13 * F_INPUT * HID + 255) / 256, 256, 0, stream>>>(Wrel1, root1, Wp1, F_INPUT);
    pack_w<<<(13 * HID * HID + 255) / 256, 256, 0, stream>>>(Wrel2, root2, Wp2, HID);
    to_bf16<<<(N_NODES * F_INPUT / 4 + 255) / 256, 256, 0, stream>>>(x, xb, N_NODES * F_INPUT / 4);
    count_nodes<<<(N_NODES + 255) / 256, 256, 0, stream>>>(batch, pcnt);

    // CSR build
    count_edges<<<(N_EDGES + 255) / 256, 256, 0, stream>>>(dstv, et, cnt);
    scan_a<<<NCHUNK, 256, 0, stream>>>(cnt, csum);
    scan_b<<<1, 1024, 0, stream>>>(csum, coff);
    scan_c<<<NCHUNK, 256, 0, stream>>>(cnt, coff, off, cursor);
    fill_csr<<<(N_EDGES + 255) / 256, 256, 0, stream>>>(srcv, dstv, et, cursor, csr);

    int nblk = (N_NODES + 63) / 64;  // 782
    rgcn_mfma<F_INPUT><<<nblk, 256, 0, stream>>>(xb, Wp1, bias1, off, csr, H1, bn1, bn1 + HID);
    bn_finalize<<<1, 128, 0, stream>>>(bn1, bn1 + HID, gamma1, beta1, bn1 + 2 * HID, bn1 + 3 * HID);
    bn_relu_bf16<<<(N_NODES * HID / 4 + 255) / 256, 256, 0, stream>>>(H1, bn1 + 2 * HID,
                                                                      bn1 + 3 * HID, H1b);

    rgcn_mfma<HID><<<nblk, 256, 0, stream>>>(H1b, Wp2, bias2, off, csr, H2, bn2, bn2 + HID);
    bn_finalize<<<1, 128, 0, stream>>>(bn2, bn2 + HID, gamma2, beta2, bn2 + 2 * HID, bn2 + 3 * HID);

    pool_bnrelu<<<(N_NODES + 15) / 16, 256, 0, stream>>>(H2, bn2 + 2 * HID, bn2 + 3 * HID,
                                                         batch, psum);
    final_kernel<<<NGRAPH, 64, 0, stream>>>(psum, pcnt, Wf, bf, (float*)d_out);
}

// Round 4
// 672.089 us; speedup vs baseline: 3.2776x; 1.0255x over previous
//
#include <hip/hip_runtime.h>

constexpr int N_NODES = 50000;
constexpr int N_EDGES = 1600000;
constexpr int NREL    = 12;
constexpr int F_INPUT = 64;
constexpr int HID     = 128;
constexpr int NCLS    = 10;
constexpr int NGRAPH  = 256;
constexpr int NSEG    = N_NODES * NREL;       // 600000
constexpr int CHUNK   = 1024;
constexpr int NCHUNK  = (NSEG + CHUNK - 1) / CHUNK;  // 586
constexpr float BN_EPS = 1e-5f;

typedef float v4f __attribute__((ext_vector_type(4)));
typedef short s8b __attribute__((ext_vector_type(8)));

__device__ __forceinline__ unsigned f2bf(float f) {
    unsigned u = __float_as_uint(f);
    return (u + 0x7FFFu + ((u >> 16) & 1u)) >> 16;   // RNE fp32->bf16
}
__device__ __forceinline__ unsigned pack2(float a, float b) {
    return f2bf(a) | (f2bf(b) << 16);
}
__device__ __forceinline__ void add8(float* a, uint4 u) {
    a[0] += __uint_as_float(u.x << 16);
    a[1] += __uint_as_float(u.x & 0xFFFF0000u);
    a[2] += __uint_as_float(u.y << 16);
    a[3] += __uint_as_float(u.y & 0xFFFF0000u);
    a[4] += __uint_as_float(u.z << 16);
    a[5] += __uint_as_float(u.z & 0xFFFF0000u);
    a[6] += __uint_as_float(u.w << 16);
    a[7] += __uint_as_float(u.w & 0xFFFF0000u);
}

// ---------------- fused prep: zero scratch + pack weights + cast x ----------------
// Segments (flat tid): cnt zero | bn1 zero | bn2 zero | psum zero | pcnt zero |
//                      pack_w1 | pack_w2 | to_bf16(x)
constexpr int PR0 = 150000;               // cnt: 600000 ints = 150000 uint4
constexpr int PR1 = PR0 + 64;             // bn1: 256 floats
constexpr int PR2 = PR1 + 64;             // bn2: 256 floats
constexpr int PR3 = PR2 + 8192;           // psum: 32768 floats
constexpr int PR4 = PR3 + 64;             // pcnt: 256 floats
constexpr int PR5 = PR4 + 13 * F_INPUT * HID;   // pack_w1: 106496
constexpr int PR6 = PR5 + 13 * HID * HID;       // pack_w2: 212992
constexpr int PR7 = PR6 + N_NODES * F_INPUT / 4; // to_bf16: 800000
constexpr int PREP_BLOCKS = (PR7 + 255) / 256;

__global__ void prep(const float* __restrict__ Wrel1, const float* __restrict__ root1,
                     const float* __restrict__ Wrel2, const float* __restrict__ root2,
                     const float* __restrict__ x,
                     ushort* __restrict__ Wp1, ushort* __restrict__ Wp2,
                     ushort* __restrict__ xb,
                     int* __restrict__ cnt, float* __restrict__ bn1, float* __restrict__ bn2,
                     float* __restrict__ psum, float* __restrict__ pcnt) {
    int tid = blockIdx.x * 256 + threadIdx.x;
    const uint4 z = make_uint4(0, 0, 0, 0);
    if (tid < PR0) { reinterpret_cast<uint4*>(cnt)[tid] = z; return; }
    if (tid < PR1) { reinterpret_cast<uint4*>(bn1)[tid - PR0] = z; return; }
    if (tid < PR2) { reinterpret_cast<uint4*>(bn2)[tid - PR1] = z; return; }
    if (tid < PR3) { reinterpret_cast<uint4*>(psum)[tid - PR2] = z; return; }
    if (tid < PR4) { reinterpret_cast<uint4*>(pcnt)[tid - PR3] = z; return; }
    if (tid < PR5) {
        int idx = tid - PR4;                       // 13 * 8192
        int r = idx >> 13, rem = idx & 8191;
        int k = rem >> 7, n = rem & 127;
        const float* W = (r < NREL) ? (Wrel1 + (size_t)r * 8192) : root1;
        float v = W[k * HID + n];
        int b = k >> 5, kk = k & 31;
        Wp1[(((size_t)(r * 2 + b)) * HID + n) * 32 + kk] = (ushort)f2bf(v);
        return;
    }
    if (tid < PR6) {
        int idx = tid - PR5;                       // 13 * 16384
        int r = idx >> 14, rem = idx & 16383;
        int k = rem >> 7, n = rem & 127;
        const float* W = (r < NREL) ? (Wrel2 + (size_t)r * 16384) : root2;
        float v = W[k * HID + n];
        int b = k >> 5, kk = k & 31;
        Wp2[(((size_t)(r * 4 + b)) * HID + n) * 32 + kk] = (ushort)f2bf(v);
        return;
    }
    if (tid < PR7) {
        int i = tid - PR6;
        float4 v = reinterpret_cast<const float4*>(x)[i];
        uint2 o;
        o.x = pack2(v.x, v.y);
        o.y = pack2(v.z, v.w);
        reinterpret_cast<uint2*>(xb)[i] = o;
    }
}

// ---------------- CSR build ----------------

constexpr int CE0 = N_EDGES / 4;          // 400000 edge-quads
constexpr int CE1 = CE0 + N_NODES / 4;    // + 12500 node-quads

__global__ void count_ek(const int* __restrict__ dst, const int* __restrict__ et,
                         int* __restrict__ cnt, const int* __restrict__ batch,
                         float* __restrict__ pcnt) {
    int tid = blockIdx.x * 256 + threadIdx.x;
    if (tid < CE0) {
        int4 d = reinterpret_cast<const int4*>(dst)[tid];
        int4 tt = reinterpret_cast<const int4*>(et)[tid];
        atomicAdd(&cnt[d.x * NREL + tt.x], 1);
        atomicAdd(&cnt[d.y * NREL + tt.y], 1);
        atomicAdd(&cnt[d.z * NREL + tt.z], 1);
        atomicAdd(&cnt[d.w * NREL + tt.w], 1);
    } else if (tid < CE1) {
        int4 b = reinterpret_cast<const int4*>(batch)[tid - CE0];
        atomicAdd(&pcnt[b.x], 1.0f);
        atomicAdd(&pcnt[b.y], 1.0f);
        atomicAdd(&pcnt[b.z], 1.0f);
        atomicAdd(&pcnt[b.w], 1.0f);
    }
}

__global__ void scan_a(const int* __restrict__ cnt, int* __restrict__ csum) {
    __shared__ int red[256];
    int b = blockIdx.x, t = threadIdx.x;
    int base = b * CHUNK + t * 4;
    int s = 0;
#pragma unroll
    for (int j = 0; j < 4; ++j) {
        int i = base + j;
        if (i < NSEG) s += cnt[i];
    }
    red[t] = s;
    __syncthreads();
    for (int d = 128; d > 0; d >>= 1) {
        if (t < d) red[t] += red[t + d];
        __syncthreads();
    }
    if (t == 0) csum[b] = red[0];
}

__global__ void scan_b(const int* __restrict__ csum, int* __restrict__ coff) {
    __shared__ int s[1024];
    int t = threadIdx.x;
    s[t] = (t < NCHUNK) ? csum[t] : 0;
    __syncthreads();
    for (int d = 1; d < 1024; d <<= 1) {
        int v = (t >= d) ? s[t - d] : 0;
        __syncthreads();
        s[t] += v;
        __syncthreads();
    }
    if (t < NCHUNK) coff[t] = (t == 0) ? 0 : s[t - 1];
}

__global__ void scan_c(const int* __restrict__ cnt, const int* __restrict__ coff,
                       int* __restrict__ off, int* __restrict__ cursor) {
    __shared__ int ts[256];
    int b = blockIdx.x, t = threadIdx.x;
    int base = b * CHUNK + t * 4;
    int c[4];
    int s = 0;
#pragma unroll
    for (int j = 0; j < 4; ++j) {
        int i = base + j;
        c[j] = (i < NSEG) ? cnt[i] : 0;
        s += c[j];
    }
    ts[t] = s;
    __syncthreads();
    for (int d = 1; d < 256; d <<= 1) {
        int v = (t >= d) ? ts[t - d] : 0;
        __syncthreads();
        ts[t] += v;
        __syncthreads();
    }
    int run = coff[b] + ((t == 0) ? 0 : ts[t - 1]);
#pragma unroll
    for (int j = 0; j < 4; ++j) {
        int i = base + j;
        if (i < NSEG) {
            off[i] = run;
            cursor[i] = run;
            run += c[j];
        }
    }
    if (b == 0 && t == 0) off[NSEG] = N_EDGES;
}

__global__ void fill_csr(const int* __restrict__ src, const int* __restrict__ dst,
                         const int* __restrict__ et, int* __restrict__ cursor,
                         int* __restrict__ csr_src) {
    int tid = blockIdx.x * 256 + threadIdx.x;
    if (tid < CE0) {
        int4 s = reinterpret_cast<const int4*>(src)[tid];
        int4 d = reinterpret_cast<const int4*>(dst)[tid];
        int4 tt = reinterpret_cast<const int4*>(et)[tid];
        csr_src[atomicAdd(&cursor[d.x * NREL + tt.x], 1)] = s.x;
        csr_src[atomicAdd(&cursor[d.y * NREL + tt.y], 1)] = s.y;
        csr_src[atomicAdd(&cursor[d.z * NREL + tt.z], 1)] = s.z;
        csr_src[atomicAdd(&cursor[d.w * NREL + tt.w], 1)] = s.w;
    }
}

// ---------------- fused RGCN layer (MFMA), 32-node tiles ----------------
// 256 threads = 4 waves. Staging: 8 threads/node, offsets preloaded to LDS,
// 2-edge unrolled independent gathers. MFMA: wave -> (row-tile rt, col-half ch),
// 4 16x16 col tiles per wave, fp32 accum. Epilogue: bias + store + BN partials.

template <int F>
__launch_bounds__(256)
__global__ void rgcn_mfma(const ushort* __restrict__ xin, const ushort* __restrict__ Wp,
                          const float* __restrict__ bias,
                          const int* __restrict__ off, const int* __restrict__ csr,
                          float* __restrict__ out, float* __restrict__ bn_sum,
                          float* __restrict__ bn_sq) {
    constexpr int TN  = 32;
    constexpr int FP2 = F + 8;       // padded LDS row (bf16 elems)
    constexpr int F8  = F / 8;       // bf16 elems per staging thread
    constexpr int NLD = F8 / 8;      // uint4 loads per staging thread (1 or 2)
    constexpr int KB  = F / 32;      // K-blocks per relation
    __shared__ __align__(16) ushort A[TN * FP2];
    __shared__ int OFF[TN][14];

    const int t = threadIdx.x;
    const int n0 = blockIdx.x * TN;
    const int nl = t >> 3, tid8 = t & 7;
    const int lane = t & 63, wave = t >> 6;
    const int q = lane >> 4, l16 = lane & 15;
    const int rt = wave & 1, ch = wave >> 1;
    const int nglob = n0 + nl;

    // preload all 13 segment boundaries for this node
    {
        bool ok = nglob < N_NODES;
        int n12 = nglob * NREL;
        OFF[nl][tid8] = ok ? off[n12 + tid8] : 0;
        if (tid8 < 5) OFF[nl][8 + tid8] = ok ? off[n12 + 8 + tid8] : 0;
    }

    v4f acc[4];
#pragma unroll
    for (int nt = 0; nt < 4; ++nt) acc[nt] = (v4f){0.f, 0.f, 0.f, 0.f};

    uint4* Aw = reinterpret_cast<uint4*>(A + nl * FP2 + tid8 * F8);
    const ushort* Arow = A + (rt * 16 + l16) * FP2;

    __syncthreads();

    for (int rel = 0; rel <= NREL; ++rel) {
        // ---- stage A tile ----
        if (rel < NREL) {
            float accs[F8];
#pragma unroll
            for (int i = 0; i < F8; ++i) accs[i] = 0.f;
            int e0 = OFF[nl][rel], e1 = OFF[nl][rel + 1];
            int e = e0;
            for (; e + 2 <= e1; e += 2) {
                int s0 = csr[e], s1 = csr[e + 1];
                const uint4* r0 = reinterpret_cast<const uint4*>(xin + (size_t)s0 * F + tid8 * F8);
                const uint4* r1 = reinterpret_cast<const uint4*>(xin + (size_t)s1 * F + tid8 * F8);
#pragma unroll
                for (int c = 0; c < NLD; ++c) {
                    uint4 u0 = r0[c];
                    uint4 u1 = r1[c];
                    add8(accs + c * 8, u0);
                    add8(accs + c * 8, u1);
                }
            }
            if (e < e1) {
                int s0 = csr[e];
                const uint4* r0 = reinterpret_cast<const uint4*>(xin + (size_t)s0 * F + tid8 * F8);
#pragma unroll
                for (int c = 0; c < NLD; ++c) {
                    uint4 u0 = r0[c];
                    add8(accs + c * 8, u0);
                }
            }
            int cntE = e1 - e0;
            float inv = (cntE > 0) ? 1.0f / (float)cntE : 0.f;
#pragma unroll
            for (int c = 0; c < NLD; ++c) {
                uint4 o;
                o.x = pack2(accs[c * 8 + 0] * inv, accs[c * 8 + 1] * inv);
                o.y = pack2(accs[c * 8 + 2] * inv, accs[c * 8 + 3] * inv);
                o.z = pack2(accs[c * 8 + 4] * inv, accs[c * 8 + 5] * inv);
                o.w = pack2(accs[c * 8 + 6] * inv, accs[c * 8 + 7] * inv);
                Aw[c] = o;
            }
        } else {  // root term: own features (already bf16)
            if (nglob < N_NODES) {
                const uint4* r0 =
                    reinterpret_cast<const uint4*>(xin + (size_t)nglob * F + tid8 * F8);
#pragma unroll
                for (int c = 0; c < NLD; ++c) Aw[c] = r0[c];
            } else {
                uint4 z = make_uint4(0, 0, 0, 0);
#pragma unroll
                for (int c = 0; c < NLD; ++c) Aw[c] = z;
            }
        }
        __syncthreads();
        // ---- MFMA accumulate ----
#pragma unroll
        for (int b = 0; b < KB; ++b) {
            s8b af = *reinterpret_cast<const s8b*>(Arow + b * 32 + q * 8);
            const ushort* wb =
                Wp + ((size_t)(rel * KB + b) * HID + ch * 64 + l16) * 32 + q * 8;
#pragma unroll
            for (int nt = 0; nt < 4; ++nt) {
                s8b bfb = *reinterpret_cast<const s8b*>(wb + (size_t)nt * 16 * 32);
                acc[nt] = __builtin_amdgcn_mfma_f32_16x16x32_bf16(af, bfb, acc[nt], 0, 0, 0);
            }
        }
        __syncthreads();
    }

    // ---- epilogue: bias + store + BN partials ----
    float* REDs = reinterpret_cast<float*>(A);       // [4][64]
    float* REDq = REDs + 256;                        // [4][64]
#pragma unroll
    for (int nt = 0; nt < 4; ++nt) {
        int col = ch * 64 + nt * 16 + l16;
        float bcol = bias[col];
        float s = 0.f, s2 = 0.f;
#pragma unroll
        for (int r = 0; r < 4; ++r) {
            int n = n0 + rt * 16 + q * 4 + r;
            if (n < N_NODES) {
                float v = acc[nt][r] + bcol;
                out[(size_t)n * HID + col] = v;
                s += v;
                s2 += v * v;
            }
        }
        s += __shfl_xor(s, 16);  s += __shfl_xor(s, 32);
        s2 += __shfl_xor(s2, 16); s2 += __shfl_xor(s2, 32);
        if (lane < 16) {
            REDs[wave * 64 + nt * 16 + l16] = s;
            REDq[wave * 64 + nt * 16 + l16] = s2;
        }
    }
    __syncthreads();
    if (t < 128) {
        int chc = t >> 6, cl = t & 63;
        float vs = REDs[(2 * chc) * 64 + cl] + REDs[(2 * chc + 1) * 64 + cl];
        float vq = REDq[(2 * chc) * 64 + cl] + REDq[(2 * chc + 1) * 64 + cl];
        atomicAdd(&bn_sum[t], vs);
        atomicAdd(&bn_sq[t], vq);
    }
}

// ---------------- BN(+finalize) + ReLU, emit bf16 ----------------

__global__ void bn_relu_bf16(const float* __restrict__ h, const float* __restrict__ bn_sum,
                             const float* __restrict__ bn_sq, const float* __restrict__ gamma,
                             const float* __restrict__ beta, ushort* __restrict__ outb) {
    __shared__ float CA[HID], CB[HID];
    int t = threadIdx.x;
    if (t < HID) {
        float mu = bn_sum[t] * (1.0f / N_NODES);
        float var = bn_sq[t] * (1.0f / N_NODES) - mu * mu;
        float a = gamma[t] / sqrtf(var + BN_EPS);
        CA[t] = a;
        CB[t] = beta[t] - a * mu;
    }
    __syncthreads();
    int i = blockIdx.x * 256 + t;  // float4 index
    constexpr int TOTAL = N_NODES * HID / 4;
    if (i < TOTAL) {
        int o4 = i & 31;
        float4 a = reinterpret_cast<const float4*>(CA)[o4];
        float4 b = reinterpret_cast<const float4*>(CB)[o4];
        float4 v = reinterpret_cast<const float4*>(h)[i];
        v.x = fmaxf(a.x * v.x + b.x, 0.f);
        v.y = fmaxf(a.y * v.y + b.y, 0.f);
        v.z = fmaxf(a.z * v.z + b.z, 0.f);
        v.w = fmaxf(a.w * v.w + b.w, 0.f);
        uint2 o;
        o.x = pack2(v.x, v.y);
        o.y = pack2(v.z, v.w);
        reinterpret_cast<uint2*>(outb)[i] = o;
    }
}

// ---------------- pooling (BN finalize + ReLU fused; batch sorted -> run-length) ----------------

__global__ void pool_bnrelu(const float* __restrict__ h, const float* __restrict__ bn_sum,
                            const float* __restrict__ bn_sq, const float* __restrict__ gamma,
                            const float* __restrict__ beta, const int* __restrict__ batch,
                            float* __restrict__ psum) {
    __shared__ float CA[HID], CB[HID];
    int t = threadIdx.x;
    if (t < HID) {
        float mu = bn_sum[t] * (1.0f / N_NODES);
        float var = bn_sq[t] * (1.0f / N_NODES) - mu * mu;
        float a = gamma[t] / sqrtf(var + BN_EPS);
        CA[t] = a;
        CB[t] = beta[t] - a * mu;
    }
    __syncthreads();
    int col = t & 127;
    int nb = blockIdx.x * 16 + (t >> 7) * 8;  // 8 consecutive nodes per thread
    float a = CA[col], b = CB[col];
    float run = 0.f;
    int curg = -1;
    for (int i = 0; i < 8; ++i) {
        int n = nb + i;
        if (n < N_NODES) {
            int g = batch[n];
            float v = fmaxf(a * h[(size_t)n * HID + col] + b, 0.f);
            if (g != curg) {
                if (curg >= 0) atomicAdd(&psum[curg * HID + col], run);
                run = 0.f;
                curg = g;
            }
            run += v;
        }
    }
    if (curg >= 0) atomicAdd(&psum[curg * HID + col], run);
}

__global__ void final_kernel(const float* __restrict__ psum, const float* __restrict__ pcnt,
                             const float* __restrict__ Wf, const float* __restrict__ bf,
                             float* __restrict__ out) {
    __shared__ float p[HID];
    int g = blockIdx.x, t = threadIdx.x;  // 64 threads
    float inv = 1.0f / fmaxf(pcnt[g], 1.0f);
    p[t] = psum[g * HID + t] * inv;
    p[t + 64] = psum[g * HID + t + 64] * inv;
    __syncthreads();
    if (t < NCLS) {
        float s = bf[t];
#pragma unroll 16
        for (int k = 0; k < HID; ++k) s += p[k] * Wf[k * NCLS + t];
        out[g * NCLS + t] = s;
    }
}

// ---------------- launch ----------------

extern "C" void kernel_launch(void* const* d_in, const int* in_sizes, int n_in,
                              void* d_out, int out_size, void* d_ws, size_t ws_size,
                              hipStream_t stream) {
    const float* x      = (const float*)d_in[0];
    const float* Wrel1  = (const float*)d_in[1];
    const float* root1  = (const float*)d_in[2];
    const float* bias1  = (const float*)d_in[3];
    const float* gamma1 = (const float*)d_in[4];
    const float* beta1  = (const float*)d_in[5];
    const float* Wrel2  = (const float*)d_in[6];
    const float* root2  = (const float*)d_in[7];
    const float* bias2  = (const float*)d_in[8];
    const float* gamma2 = (const float*)d_in[9];
    const float* beta2  = (const float*)d_in[10];
    const float* Wf     = (const float*)d_in[11];
    const float* bf     = (const float*)d_in[12];
    const int* ei       = (const int*)d_in[13];
    const int* et       = (const int*)d_in[14];
    const int* batch    = (const int*)d_in[15];
    const int* srcv = ei;
    const int* dstv = ei + N_EDGES;

    char* w = (char*)d_ws;
    auto alloc = [&](size_t bytes) -> char* {
        char* p = w;
        w += (bytes + 255) / 256 * 256;
        return p;
    };
    int* cnt     = (int*)alloc((size_t)NSEG * 4);
    int* off     = (int*)alloc((size_t)(NSEG + 1) * 4);
    int* cursor  = (int*)alloc((size_t)NSEG * 4);
    int* csr     = (int*)alloc((size_t)N_EDGES * 4);
    int* csum    = (int*)alloc((size_t)NCHUNK * 4);
    int* coff    = (int*)alloc((size_t)NCHUNK * 4);
    float* H1    = (float*)alloc((size_t)N_NODES * HID * 4);
    float* H2    = (float*)alloc((size_t)N_NODES * HID * 4);
    ushort* xb   = (ushort*)alloc((size_t)N_NODES * F_INPUT * 2);
    ushort* H1b  = (ushort*)alloc((size_t)N_NODES * HID * 2);
    ushort* Wp1  = (ushort*)alloc((size_t)13 * F_INPUT * HID * 2);
    ushort* Wp2  = (ushort*)alloc((size_t)13 * HID * HID * 2);
    float* bn1   = (float*)alloc(2 * HID * 4);  // sum | sq
    float* bn2   = (float*)alloc(2 * HID * 4);
    float* psum  = (float*)alloc((size_t)NGRAPH * HID * 4);
    float* pcnt  = (float*)alloc((size_t)NGRAPH * 4);

    prep<<<PREP_BLOCKS, 256, 0, stream>>>(Wrel1, root1, Wrel2, root2, x,
                                          Wp1, Wp2, xb, cnt, bn1, bn2, psum, pcnt);

    count_ek<<<(CE1 + 255) / 256, 256, 0, stream>>>(dstv, et, cnt, batch, pcnt);
    scan_a<<<NCHUNK, 256, 0, stream>>>(cnt, csum);
    scan_b<<<1, 1024, 0, stream>>>(csum, coff);
    scan_c<<<NCHUNK, 256, 0, stream>>>(cnt, coff, off, cursor);
    fill_csr<<<(CE0 + 255) / 256, 256, 0, stream>>>(srcv, dstv, et, cursor, csr);

    int nblk = (N_NODES + 31) / 32;  // 1563
    rgcn_mfma<F_INPUT><<<nblk, 256, 0, stream>>>(xb, Wp1, bias1, off, csr, H1, bn1, bn1 + HID);
    bn_relu_bf16<<<(N_NODES * HID / 4 + 255) / 256, 256, 0, stream>>>(H1, bn1, bn1 + HID,
                                                                      gamma1, beta1, H1b);

    rgcn_mfma<HID><<<nblk, 256, 0, stream>>>(H1b, Wp2, bias2, off, csr, H2, bn2, bn2 + HID);

    pool_bnrelu<<<(N_NODES + 15) / 16, 256, 0, stream>>>(H2, bn2, bn2 + HID, gamma2, beta2,
                                                         batch, psum);
    final_kernel<<<NGRAPH, 64, 0, stream>>>(psum, pcnt, Wf, bf, (float*)d_out);
}